// Round 1
// baseline (214.592 us; speedup 1.0000x reference)
//
#include <hip/hip_runtime.h>
#include <hip/hip_bf16.h>
#include <math.h>

#define B_  4
#define S_  4096
#define D_  1024
#define M_  (B_ * S_)   // 16384 rows
#define K_  D_          // 1024 reduction
#define L_  64          // scan chunk length
#define NC_ (S_ / L_)   // 64 chunks per sequence

typedef __attribute__((ext_vector_type(8))) short  bf16x8;
typedef __attribute__((ext_vector_type(4))) float  f32x4;

__device__ __forceinline__ float softplus_f(float x) {
    // stable: max(x,0) + log1p(exp(-|x|))
    return fmaxf(x, 0.0f) + __logf(1.0f + __expf(-fabsf(x)));
}

__device__ __forceinline__ unsigned short f2bf(float f) {
    __hip_bfloat16 h = __float2bfloat16(f);
    union { __hip_bfloat16 h; unsigned short u; } cv;
    cv.h = h;
    return cv.u;
}

// logaddexp(u, v), u may be -inf (then returns v)
__device__ __forceinline__ float logaddexp_f(float u, float v) {
    float m = fmaxf(u, v);
    return m + __logf(1.0f + __expf(-fabsf(u - v)));
}

// ---------------------------------------------------------------------------
// Kernel 1: bf16 MFMA GEMM (x[M,K] * W[N,K]^T) fused with the pointwise
// log-space transform. Each block computes a 128(m) x 64(d) tile of BOTH
// hidden (W rows d0..d0+63) and gate (W rows 1024+d0..1024+d0+63), so the
// (hidden, gate) pair for a given (m,d) lives in the same lane/register.
// Outputs: lc[m,d] = -softplus(gate), lv[m,d] = -softplus(-gate)+log_g(hidden)
// ---------------------------------------------------------------------------
__global__ __launch_bounds__(256, 2) void gemm_pointwise(
    const float* __restrict__ x, const float* __restrict__ W,
    float* __restrict__ lcbuf, float* __restrict__ lvbuf)
{
    // LDS tiles, padded to 40 ushorts (80B row stride) to kill ds_read_b128
    // bank conflicts while keeping 16B alignment.
    __shared__ unsigned short As[128][40];
    __shared__ unsigned short Bs[128][40];

    const int tid  = threadIdx.x;
    const int lane = tid & 63;
    const int wave = tid >> 6;
    const int wm = wave >> 1;      // 0..1 -> m offset 0/64
    const int wn = wave & 1;       // 0..1 -> d offset 0/32
    const int m0 = blockIdx.y * 128;
    const int d0 = blockIdx.x * 64;

    f32x4 acc_h[4][2], acc_g[4][2];
#pragma unroll
    for (int mi = 0; mi < 4; ++mi)
#pragma unroll
        for (int ni = 0; ni < 2; ++ni) {
            acc_h[mi][ni] = (f32x4){0.f, 0.f, 0.f, 0.f};
            acc_g[mi][ni] = (f32x4){0.f, 0.f, 0.f, 0.f};
        }

    const int kq      = (tid & 7) * 4;   // float offset within 32-wide K tile
    const int rowbase = tid >> 3;        // 0..31

    float4 areg[4], breg[4];

    // prefetch K-tile 0
#pragma unroll
    for (int p = 0; p < 4; ++p) {
        int r = rowbase + 32 * p;
        areg[p] = *(const float4*)(x + (size_t)(m0 + r) * K_ + kq);
        int wr = (r < 64) ? (d0 + r) : (D_ + d0 + (r - 64));
        breg[p] = *(const float4*)(W + (size_t)wr * K_ + kq);
    }

    const int lr = lane & 15;
    const int lk = (lane >> 4) * 8;      // bf16 element offset within row

    for (int kt = 0; kt < K_ / 32; ++kt) {
        __syncthreads();   // all waves done reading previous LDS tile
#pragma unroll
        for (int p = 0; p < 4; ++p) {
            int r = rowbase + 32 * p;
            ushort4 pa, pb;
            pa.x = f2bf(areg[p].x); pa.y = f2bf(areg[p].y);
            pa.z = f2bf(areg[p].z); pa.w = f2bf(areg[p].w);
            pb.x = f2bf(breg[p].x); pb.y = f2bf(breg[p].y);
            pb.z = f2bf(breg[p].z); pb.w = f2bf(breg[p].w);
            *(ushort4*)&As[r][kq] = pa;
            *(ushort4*)&Bs[r][kq] = pb;
        }
        __syncthreads();

        // issue next tile's global loads (latency hides under MFMAs below)
        if (kt + 1 < K_ / 32) {
            const int k0 = (kt + 1) * 32;
#pragma unroll
            for (int p = 0; p < 4; ++p) {
                int r = rowbase + 32 * p;
                areg[p] = *(const float4*)(x + (size_t)(m0 + r) * K_ + k0 + kq);
                int wr = (r < 64) ? (d0 + r) : (D_ + d0 + (r - 64));
                breg[p] = *(const float4*)(W + (size_t)wr * K_ + k0 + kq);
            }
        }

        bf16x8 af[4], bh[2], bg[2];
#pragma unroll
        for (int mi = 0; mi < 4; ++mi)
            af[mi] = *(const bf16x8*)&As[wm * 64 + mi * 16 + lr][lk];
#pragma unroll
        for (int ni = 0; ni < 2; ++ni) {
            bh[ni] = *(const bf16x8*)&Bs[wn * 32 + ni * 16 + lr][lk];
            bg[ni] = *(const bf16x8*)&Bs[64 + wn * 32 + ni * 16 + lr][lk];
        }
#pragma unroll
        for (int mi = 0; mi < 4; ++mi)
#pragma unroll
            for (int ni = 0; ni < 2; ++ni) {
                acc_h[mi][ni] = __builtin_amdgcn_mfma_f32_16x16x32_bf16(
                    af[mi], bh[ni], acc_h[mi][ni], 0, 0, 0);
                acc_g[mi][ni] = __builtin_amdgcn_mfma_f32_16x16x32_bf16(
                    af[mi], bg[ni], acc_g[mi][ni], 0, 0, 0);
            }
    }

    // epilogue: pointwise transform + store
    // C/D layout: col = lane&15, row = (lane>>4)*4 + reg   [measured m89/m91]
#pragma unroll
    for (int mi = 0; mi < 4; ++mi)
#pragma unroll
        for (int ni = 0; ni < 2; ++ni)
#pragma unroll
            for (int r = 0; r < 4; ++r) {
                int m = m0 + wm * 64 + mi * 16 + ((lane >> 4) << 2) + r;
                int d = d0 + wn * 32 + ni * 16 + (lane & 15);
                float h = acc_h[mi][ni][r];
                float g = acc_g[mi][ni][r];
                float lc = -softplus_f(g);
                float lgh = (h >= 0.0f) ? __logf(h + 0.5f) : -softplus_f(-h);
                float lv = -softplus_f(-g) + lgh;
                lcbuf[(size_t)m * D_ + d] = lc;
                lvbuf[(size_t)m * D_ + d] = lv;
            }
}

// ---------------------------------------------------------------------------
// Kernel 2: per-chunk reduce. State (A, lb): h_out = e^A * h_in + e^lb.
// ---------------------------------------------------------------------------
__global__ void chunk_reduce(const float* __restrict__ lcbuf,
                             const float* __restrict__ lvbuf,
                             float* __restrict__ Aagg,
                             float* __restrict__ lBagg)
{
    const int d = blockIdx.x * 256 + threadIdx.x;
    const int c = blockIdx.y;
    const int b = blockIdx.z;
    size_t base = ((size_t)(b * S_ + c * L_)) * D_ + d;
    float A = 0.0f, lb = -INFINITY;
    for (int s = 0; s < L_; ++s) {
        float lc = lcbuf[base + (size_t)s * D_];
        float lv = lvbuf[base + (size_t)s * D_];
        A += lc;
        lb = logaddexp_f(lb + lc, lv);
    }
    size_t o = ((size_t)b * NC_ + c) * D_ + d;
    Aagg[o] = A;
    lBagg[o] = lb;
}

// ---------------------------------------------------------------------------
// Kernel 3: scan across chunks (NC_=64 steps, tiny). P[c] = log h at entry.
// ---------------------------------------------------------------------------
__global__ void chunk_scan(const float* __restrict__ Aagg,
                           const float* __restrict__ lBagg,
                           float* __restrict__ P)
{
    const int d = blockIdx.x * 256 + threadIdx.x;
    const int b = blockIdx.z;
    float p = -INFINITY;
    for (int c = 0; c < NC_; ++c) {
        size_t o = ((size_t)b * NC_ + c) * D_ + d;
        P[o] = p;
        p = logaddexp_f(Aagg[o] + p, lBagg[o]);
    }
}

// ---------------------------------------------------------------------------
// Kernel 4: re-run local scan applying chunk prefix; out = e^(a+p) + e^lb
// ---------------------------------------------------------------------------
__global__ void chunk_apply(const float* __restrict__ lcbuf,
                            const float* __restrict__ lvbuf,
                            const float* __restrict__ P,
                            float* __restrict__ out)
{
    const int d = blockIdx.x * 256 + threadIdx.x;
    const int c = blockIdx.y;
    const int b = blockIdx.z;
    size_t base = ((size_t)(b * S_ + c * L_)) * D_ + d;
    float p = P[((size_t)b * NC_ + c) * D_ + d];
    float a = 0.0f, lb = -INFINITY;
    for (int s = 0; s < L_; ++s) {
        float lc = lcbuf[base + (size_t)s * D_];
        float lv = lvbuf[base + (size_t)s * D_];
        a += lc;
        lb = logaddexp_f(lb + lc, lv);
        out[base + (size_t)s * D_] = __expf(a + p) + __expf(lb);
    }
}

extern "C" void kernel_launch(void* const* d_in, const int* in_sizes, int n_in,
                              void* d_out, int out_size, void* d_ws, size_t ws_size,
                              hipStream_t stream) {
    const float* x = (const float*)d_in[0];   // [B,S,D] fp32
    const float* W = (const float*)d_in[1];   // [2D,D] fp32
    float* out = (float*)d_out;               // [B,S,D] fp32

    float* lcbuf = (float*)d_ws;                       // M*D
    float* lvbuf = lcbuf + (size_t)M_ * D_;            // M*D
    float* Aagg  = lvbuf + (size_t)M_ * D_;            // B*NC*D
    float* lBagg = Aagg  + (size_t)B_ * NC_ * D_;      // B*NC*D
    float* P     = lBagg + (size_t)B_ * NC_ * D_;      // B*NC*D

    dim3 g1(D_ / 64, M_ / 128, 1);    // 16 x 128 blocks
    gemm_pointwise<<<g1, 256, 0, stream>>>(x, W, lcbuf, lvbuf);

    dim3 g2(D_ / 256, NC_, B_);       // 4 x 64 x 4
    chunk_reduce<<<g2, 256, 0, stream>>>(lcbuf, lvbuf, Aagg, lBagg);

    dim3 g3(D_ / 256, 1, B_);         // 4 x 1 x 4
    chunk_scan<<<g3, 256, 0, stream>>>(Aagg, lBagg, P);

    chunk_apply<<<g2, 256, 0, stream>>>(lcbuf, lvbuf, P, out);
}

// Round 2
// 192.537 us; speedup vs baseline: 1.1145x; 1.1145x over previous
//
#include <hip/hip_runtime.h>
#include <hip/hip_bf16.h>
#include <math.h>

#define B_  4
#define S_  4096
#define D_  1024
#define M_  (B_ * S_)   // 16384 rows
#define K_  D_          // 1024 reduction
#define L_  64          // scan chunk length
#define NC_ (S_ / L_)   // 64 chunks per sequence
#define NT_ (K_ / 32)   // 32 K-steps

typedef __attribute__((ext_vector_type(8))) short          bf16x8;
typedef __attribute__((ext_vector_type(8))) unsigned short u16x8;
typedef __attribute__((ext_vector_type(4))) float          f32x4;

__device__ __forceinline__ float softplus_f(float x) {
    return fmaxf(x, 0.0f) + __logf(1.0f + __expf(-fabsf(x)));
}

__device__ __forceinline__ unsigned short f2bf(float f) {
    union { __hip_bfloat16 h; unsigned short u; } cv;
    cv.h = __float2bfloat16(f);
    return cv.u;
}

__device__ __forceinline__ float logaddexp_f(float u, float v) {
    float m = fmaxf(u, v);
    return m + __logf(1.0f + __expf(-fabsf(u - v)));
}

// ---------------------------------------------------------------------------
// Kernel 0: fp32 -> bf16 pre-convert (memory-bound, vectorized 8/thread)
// ---------------------------------------------------------------------------
__global__ __launch_bounds__(256) void to_bf16(
    const float* __restrict__ in, unsigned short* __restrict__ out, int n8)
{
    int i = blockIdx.x * 256 + threadIdx.x;
    if (i >= n8) return;
    const float4* p = (const float4*)in + (size_t)i * 2;
    float4 a = p[0], b = p[1];
    u16x8 o;
    o[0] = f2bf(a.x); o[1] = f2bf(a.y); o[2] = f2bf(a.z); o[3] = f2bf(a.w);
    o[4] = f2bf(b.x); o[5] = f2bf(b.y); o[6] = f2bf(b.z); o[7] = f2bf(b.w);
    *(u16x8*)(out + (size_t)i * 8) = o;
}

// ---------------------------------------------------------------------------
// Kernel 1: bf16 MFMA GEMM (m97 structure: global_load_lds w=16, double-buffer
// LDS, one barrier per K-step) fused with the log-space pointwise transform.
// Block tile: 128(m) x [64 hidden d-cols + 64 gate d-cols]. Each wave's 4
// N-frags = 2 hidden + 2 gate at the SAME d, so (h,g) pair per-lane.
// ---------------------------------------------------------------------------
__global__ __launch_bounds__(256, 3) void gemm_pointwise(
    const unsigned short* __restrict__ xb, const unsigned short* __restrict__ Wb,
    float* __restrict__ lcbuf, float* __restrict__ lvbuf)
{
    // linear layout (required by global_load_lds): row stride 32 bf16 = 64B
    __shared__ unsigned short As[2][128][32];
    __shared__ unsigned short Bs[2][128][32];

    const int tid  = threadIdx.x;
    const int lane = tid & 63;
    const int wave = tid >> 6;
    const int wm = wave >> 1;      // m offset 0/64
    const int wn = wave & 1;       // d offset 0/32
    const int m0 = blockIdx.y * 128;
    const int d0 = blockIdx.x * 64;

    f32x4 acc[4][4];
#pragma unroll
    for (int mi = 0; mi < 4; ++mi)
#pragma unroll
        for (int ni = 0; ni < 4; ++ni)
            acc[mi][ni] = (f32x4){0.f, 0.f, 0.f, 0.f};

    // staging geometry: 256 thr x 16B = 4KB = 64 rows per issue, 2 issues/tile
    const int srow = tid >> 2;            // 0..63
    const int scol = (tid & 3) * 8;       // bf16 col within 32-wide K tile
    const unsigned short* ga0 = xb + (size_t)(m0 + srow)       * K_ + scol;
    const unsigned short* ga1 = xb + (size_t)(m0 + 64 + srow)  * K_ + scol;
    const unsigned short* gb0 = Wb + (size_t)(d0 + srow)       * K_ + scol;  // hidden rows
    const unsigned short* gb1 = Wb + (size_t)(D_ + d0 + srow)  * K_ + scol;  // gate rows
    // wave-uniform LDS bases: wave w writes rows [j*64 + w*16, +16)
    char* lA = (char*)&As[0][0][0] + wave * 1024;
    char* lB = (char*)&Bs[0][0][0] + wave * 1024;

#define STAGE(buf, kt) do {                                                          \
    const int ko = (kt) * 32;                                                        \
    __builtin_amdgcn_global_load_lds(                                                \
        (const __attribute__((address_space(1))) unsigned int*)(ga0 + ko),           \
        (__attribute__((address_space(3))) unsigned int*)(lA + (buf) * 8192),        \
        16, 0, 0);                                                                   \
    __builtin_amdgcn_global_load_lds(                                                \
        (const __attribute__((address_space(1))) unsigned int*)(ga1 + ko),           \
        (__attribute__((address_space(3))) unsigned int*)(lA + (buf) * 8192 + 4096), \
        16, 0, 0);                                                                   \
    __builtin_amdgcn_global_load_lds(                                                \
        (const __attribute__((address_space(1))) unsigned int*)(gb0 + ko),           \
        (__attribute__((address_space(3))) unsigned int*)(lB + (buf) * 8192),        \
        16, 0, 0);                                                                   \
    __builtin_amdgcn_global_load_lds(                                                \
        (const __attribute__((address_space(1))) unsigned int*)(gb1 + ko),           \
        (__attribute__((address_space(3))) unsigned int*)(lB + (buf) * 8192 + 4096), \
        16, 0, 0);                                                                   \
  } while (0)

    const int lr  = lane & 15;
    const int lkb = (lane >> 4) * 16;    // byte offset of this lane's 8 bf16

    STAGE(0, 0);
    __syncthreads();   // drains vmcnt(0) then barrier

    int cur = 0;
    for (int kt = 0; kt < NT_; ++kt) {
        if (kt + 1 < NT_) STAGE(cur ^ 1, kt + 1);   // prefetch flies under MFMA

        bf16x8 af[4], bfr[4];
        const char* Ab = (const char*)&As[cur][0][0];
        const char* Bb = (const char*)&Bs[cur][0][0];
#pragma unroll
        for (int mi = 0; mi < 4; ++mi)
            af[mi] = *(const bf16x8*)(Ab + (wm * 64 + mi * 16 + lr) * 64 + lkb);
#pragma unroll
        for (int ni = 0; ni < 2; ++ni) {
            bfr[ni]     = *(const bf16x8*)(Bb + (wn * 32 + ni * 16 + lr) * 64 + lkb);
            bfr[ni + 2] = *(const bf16x8*)(Bb + (64 + wn * 32 + ni * 16 + lr) * 64 + lkb);
        }
#pragma unroll
        for (int mi = 0; mi < 4; ++mi)
#pragma unroll
            for (int ni = 0; ni < 4; ++ni)
                acc[mi][ni] = __builtin_amdgcn_mfma_f32_16x16x32_bf16(
                    af[mi], bfr[ni], acc[mi][ni], 0, 0, 0);

        __syncthreads();   // ds_reads done + prefetch landed before swap
        cur ^= 1;
    }
#undef STAGE

    // epilogue: pointwise transform + store
    // C/D layout: col = lane&15 (B index), row = (lane>>4)*4 + reg (A index)
#pragma unroll
    for (int mi = 0; mi < 4; ++mi)
#pragma unroll
        for (int ni = 0; ni < 2; ++ni)
#pragma unroll
            for (int r = 0; r < 4; ++r) {
                int m = m0 + wm * 64 + mi * 16 + ((lane >> 4) << 2) + r;
                int d = d0 + wn * 32 + ni * 16 + (lane & 15);
                float h = acc[mi][ni][r];       // hidden frag
                float g = acc[mi][ni + 2][r];   // gate frag, same d
                float lc = -softplus_f(g);
                float lgh = (h >= 0.0f) ? __logf(h + 0.5f) : -softplus_f(-h);
                float lv = -softplus_f(-g) + lgh;
                lcbuf[(size_t)m * D_ + d] = lc;
                lvbuf[(size_t)m * D_ + d] = lv;
            }
}

// ---------------------------------------------------------------------------
// Kernel 2: per-chunk reduce. State (A, lb): h_out = e^A * h_in + e^lb.
// ---------------------------------------------------------------------------
__global__ void chunk_reduce(const float* __restrict__ lcbuf,
                             const float* __restrict__ lvbuf,
                             float* __restrict__ Aagg,
                             float* __restrict__ lBagg)
{
    const int d = blockIdx.x * 256 + threadIdx.x;
    const int c = blockIdx.y;
    const int b = blockIdx.z;
    size_t base = ((size_t)(b * S_ + c * L_)) * D_ + d;
    float A = 0.0f, lb = -INFINITY;
    for (int s = 0; s < L_; ++s) {
        float lc = lcbuf[base + (size_t)s * D_];
        float lv = lvbuf[base + (size_t)s * D_];
        A += lc;
        lb = logaddexp_f(lb + lc, lv);
    }
    size_t o = ((size_t)b * NC_ + c) * D_ + d;
    Aagg[o] = A;
    lBagg[o] = lb;
}

// ---------------------------------------------------------------------------
// Kernel 3: scan across chunks (NC_=64 steps, tiny). P[c] = log h at entry.
// ---------------------------------------------------------------------------
__global__ void chunk_scan(const float* __restrict__ Aagg,
                           const float* __restrict__ lBagg,
                           float* __restrict__ P)
{
    const int d = blockIdx.x * 256 + threadIdx.x;
    const int b = blockIdx.z;
    float p = -INFINITY;
    for (int c = 0; c < NC_; ++c) {
        size_t o = ((size_t)b * NC_ + c) * D_ + d;
        P[o] = p;
        p = logaddexp_f(Aagg[o] + p, lBagg[o]);
    }
}

// ---------------------------------------------------------------------------
// Kernel 4: re-run local scan applying chunk prefix; out = e^(a+p) + e^lb
// ---------------------------------------------------------------------------
__global__ void chunk_apply(const float* __restrict__ lcbuf,
                            const float* __restrict__ lvbuf,
                            const float* __restrict__ P,
                            float* __restrict__ out)
{
    const int d = blockIdx.x * 256 + threadIdx.x;
    const int c = blockIdx.y;
    const int b = blockIdx.z;
    size_t base = ((size_t)(b * S_ + c * L_)) * D_ + d;
    float p = P[((size_t)b * NC_ + c) * D_ + d];
    float a = 0.0f, lb = -INFINITY;
    for (int s = 0; s < L_; ++s) {
        float lc = lcbuf[base + (size_t)s * D_];
        float lv = lvbuf[base + (size_t)s * D_];
        a += lc;
        lb = logaddexp_f(lb + lc, lv);
        out[base + (size_t)s * D_] = __expf(a + p) + __expf(lb);
    }
}

extern "C" void kernel_launch(void* const* d_in, const int* in_sizes, int n_in,
                              void* d_out, int out_size, void* d_ws, size_t ws_size,
                              hipStream_t stream) {
    const float* x = (const float*)d_in[0];   // [B,S,D] fp32
    const float* W = (const float*)d_in[1];   // [2D,D] fp32
    float* out = (float*)d_out;               // [B,S,D] fp32

    float* lcbuf = (float*)d_ws;                          // M*D f32
    float* lvbuf = lcbuf + (size_t)M_ * D_;               // M*D f32
    float* Aagg  = lvbuf + (size_t)M_ * D_;               // B*NC*D
    float* lBagg = Aagg  + (size_t)B_ * NC_ * D_;
    float* P     = lBagg + (size_t)B_ * NC_ * D_;
    unsigned short* xb = (unsigned short*)(P + (size_t)B_ * NC_ * D_);  // M*K bf16
    unsigned short* Wb = xb + (size_t)M_ * K_;                          // 2D*K bf16

    const int nx8 = M_ * K_ / 8;          // 2,097,152
    const int nw8 = 2 * D_ * K_ / 8;      // 262,144
    to_bf16<<<(nx8 + 255) / 256, 256, 0, stream>>>(x, xb, nx8);
    to_bf16<<<(nw8 + 255) / 256, 256, 0, stream>>>(W, Wb, nw8);

    dim3 g1(D_ / 64, M_ / 128, 1);        // 16 x 128 blocks
    gemm_pointwise<<<g1, 256, 0, stream>>>(xb, Wb, lcbuf, lvbuf);

    dim3 g2(D_ / 256, NC_, B_);           // 4 x 64 x 4
    chunk_reduce<<<g2, 256, 0, stream>>>(lcbuf, lvbuf, Aagg, lBagg);

    dim3 g3(D_ / 256, 1, B_);             // 4 x 1 x 4
    chunk_scan<<<g3, 256, 0, stream>>>(Aagg, lBagg, P);

    chunk_apply<<<g2, 256, 0, stream>>>(lcbuf, lvbuf, P, out);
}

// Round 3
// 184.391 us; speedup vs baseline: 1.1638x; 1.0442x over previous
//
#include <hip/hip_runtime.h>
#include <hip/hip_bf16.h>
#include <hip/hip_fp16.h>
#include <math.h>

#define B_  4
#define S_  4096
#define D_  1024
#define M_  (B_ * S_)   // 16384 rows
#define K_  D_          // 1024 reduction
#define L_  64          // scan chunk length
#define NC_ (S_ / L_)   // 64 chunks per sequence
#define NT_ (K_ / 32)   // 32 K-steps

typedef __attribute__((ext_vector_type(8))) short          bf16x8;
typedef __attribute__((ext_vector_type(8))) unsigned short u16x8;
typedef __attribute__((ext_vector_type(4))) float          f32x4;

__device__ __forceinline__ float softplus_f(float x) {
    return fmaxf(x, 0.0f) + __logf(1.0f + __expf(-fabsf(x)));
}

__device__ __forceinline__ unsigned short f2bf(float f) {
    union { __hip_bfloat16 h; unsigned short u; } cv;
    cv.h = __float2bfloat16(f);
    return cv.u;
}

__device__ __forceinline__ float h2f(unsigned short u) {
    union { __half h; unsigned short u; } cv;
    cv.u = u;
    return __half2float(cv.h);
}

__device__ __forceinline__ float logaddexp_f(float u, float v) {
    float m = fmaxf(u, v);
    return m + __logf(1.0f + __expf(-fabsf(u - v)));
}

// ---------------------------------------------------------------------------
// Kernel 0: fp32 -> bf16 pre-convert (memory-bound, vectorized 8/thread)
// ---------------------------------------------------------------------------
__global__ __launch_bounds__(256) void to_bf16(
    const float* __restrict__ in, unsigned short* __restrict__ out, int n8)
{
    int i = blockIdx.x * 256 + threadIdx.x;
    if (i >= n8) return;
    const float4* p = (const float4*)in + (size_t)i * 2;
    float4 a = p[0], b = p[1];
    u16x8 o;
    o[0] = f2bf(a.x); o[1] = f2bf(a.y); o[2] = f2bf(a.z); o[3] = f2bf(a.w);
    o[4] = f2bf(b.x); o[5] = f2bf(b.y); o[6] = f2bf(b.z); o[7] = f2bf(b.w);
    *(u16x8*)(out + (size_t)i * 8) = o;
}

// ---------------------------------------------------------------------------
// Kernel 1: bf16 MFMA GEMM, m97 structure + bank-conflict swizzle.
// LDS rows are 64B (32 bf16). Logical (row r, 16B-col c) lives at LDS byte
// r*64 + (c ^ ((r>>1)&3))*16. global_load_lds writes linearly, so the STAGE
// source address applies the same XOR (rule #21: both-sides-or-neither).
// 16 lanes/quarter then hit each of the 8 bank-slots exactly twice -> free.
// ---------------------------------------------------------------------------
__global__ __launch_bounds__(256, 3) void gemm_pointwise(
    const unsigned short* __restrict__ xb, const unsigned short* __restrict__ Wb,
    __half* __restrict__ lcbuf, __half* __restrict__ lvbuf)
{
    __shared__ unsigned short As[2][128][32];
    __shared__ unsigned short Bs[2][128][32];

    const int tid  = threadIdx.x;
    const int lane = tid & 63;
    const int wave = tid >> 6;
    const int wm = wave >> 1;      // m offset 0/64
    const int wn = wave & 1;       // d offset 0/32
    const int m0 = blockIdx.y * 128;
    const int d0 = blockIdx.x * 64;

    f32x4 acc[4][4];
#pragma unroll
    for (int mi = 0; mi < 4; ++mi)
#pragma unroll
        for (int ni = 0; ni < 4; ++ni)
            acc[mi][ni] = (f32x4){0.f, 0.f, 0.f, 0.f};

    // staging: 256 thr x 16B = 64 rows per issue; source col pre-swizzled
    const int srow = tid >> 2;                              // 0..63
    const int scol = (((tid & 3) ^ ((tid >> 3) & 3)) * 8);  // swizzled bf16 col
    const unsigned short* ga0 = xb + (size_t)(m0 + srow)      * K_ + scol;
    const unsigned short* ga1 = xb + (size_t)(m0 + 64 + srow) * K_ + scol;
    const unsigned short* gb0 = Wb + (size_t)(d0 + srow)      * K_ + scol;  // hidden
    const unsigned short* gb1 = Wb + (size_t)(D_ + d0 + srow) * K_ + scol;  // gate
    char* lA = (char*)&As[0][0][0] + wave * 1024;
    char* lB = (char*)&Bs[0][0][0] + wave * 1024;

#define STAGE(buf, kt) do {                                                          \
    const int ko = (kt) * 32;                                                        \
    __builtin_amdgcn_global_load_lds(                                                \
        (const __attribute__((address_space(1))) unsigned int*)(ga0 + ko),           \
        (__attribute__((address_space(3))) unsigned int*)(lA + (buf) * 8192),        \
        16, 0, 0);                                                                   \
    __builtin_amdgcn_global_load_lds(                                                \
        (const __attribute__((address_space(1))) unsigned int*)(ga1 + ko),           \
        (__attribute__((address_space(3))) unsigned int*)(lA + (buf) * 8192 + 4096), \
        16, 0, 0);                                                                   \
    __builtin_amdgcn_global_load_lds(                                                \
        (const __attribute__((address_space(1))) unsigned int*)(gb0 + ko),           \
        (__attribute__((address_space(3))) unsigned int*)(lB + (buf) * 8192),        \
        16, 0, 0);                                                                   \
    __builtin_amdgcn_global_load_lds(                                                \
        (const __attribute__((address_space(1))) unsigned int*)(gb1 + ko),           \
        (__attribute__((address_space(3))) unsigned int*)(lB + (buf) * 8192 + 4096), \
        16, 0, 0);                                                                   \
  } while (0)

    const int lr = lane & 15;
    // swizzled read offset: 16B-col (lane>>4) XOR'd with ((row>>1)&3) = ((lr>>1)&3)
    const int lkb = (((lane >> 4) ^ ((lr >> 1) & 3)) * 16);

    STAGE(0, 0);
    __syncthreads();

    int cur = 0;
    for (int kt = 0; kt < NT_; ++kt) {
        if (kt + 1 < NT_) STAGE(cur ^ 1, kt + 1);

        bf16x8 af[4], bfr[4];
        const char* Ab = (const char*)&As[cur][0][0];
        const char* Bb = (const char*)&Bs[cur][0][0];
#pragma unroll
        for (int mi = 0; mi < 4; ++mi)
            af[mi] = *(const bf16x8*)(Ab + (wm * 64 + mi * 16 + lr) * 64 + lkb);
#pragma unroll
        for (int ni = 0; ni < 2; ++ni) {
            bfr[ni]     = *(const bf16x8*)(Bb + (wn * 32 + ni * 16 + lr) * 64 + lkb);
            bfr[ni + 2] = *(const bf16x8*)(Bb + (64 + wn * 32 + ni * 16 + lr) * 64 + lkb);
        }
#pragma unroll
        for (int mi = 0; mi < 4; ++mi)
#pragma unroll
            for (int ni = 0; ni < 4; ++ni)
                acc[mi][ni] = __builtin_amdgcn_mfma_f32_16x16x32_bf16(
                    af[mi], bfr[ni], acc[mi][ni], 0, 0, 0);

        __syncthreads();
        cur ^= 1;
    }
#undef STAGE

    // epilogue: pointwise transform + fp16 store
#pragma unroll
    for (int mi = 0; mi < 4; ++mi)
#pragma unroll
        for (int ni = 0; ni < 2; ++ni)
#pragma unroll
            for (int r = 0; r < 4; ++r) {
                int m = m0 + wm * 64 + mi * 16 + ((lane >> 4) << 2) + r;
                int d = d0 + wn * 32 + ni * 16 + (lane & 15);
                float h = acc[mi][ni][r];       // hidden frag
                float g = acc[mi][ni + 2][r];   // gate frag, same d
                float lc = -softplus_f(g);
                float lgh = (h >= 0.0f) ? __logf(h + 0.5f) : -softplus_f(-h);
                float lv = -softplus_f(-g) + lgh;
                lcbuf[(size_t)m * D_ + d] = __float2half(lc);
                lvbuf[(size_t)m * D_ + d] = __float2half(lv);
            }
}

// ---------------------------------------------------------------------------
// Kernel 2: per-chunk reduce, 4 d-channels per thread (8B fp16 loads).
// State (A, lb): h_out = e^A * h_in + e^lb.
// ---------------------------------------------------------------------------
__global__ __launch_bounds__(256) void chunk_reduce(
    const __half* __restrict__ lcbuf, const __half* __restrict__ lvbuf,
    float* __restrict__ Aagg, float* __restrict__ lBagg)
{
    const int d = threadIdx.x * 4;          // 256 thr x 4 = 1024 = D_
    const int c = blockIdx.y;
    const int b = blockIdx.z;
    size_t base = ((size_t)(b * S_ + c * L_)) * D_ + d;
    float A[4] = {0.f, 0.f, 0.f, 0.f};
    float lb[4] = {-INFINITY, -INFINITY, -INFINITY, -INFINITY};
    for (int s = 0; s < L_; ++s) {
        ushort4 lc4 = *(const ushort4*)(lcbuf + base + (size_t)s * D_);
        ushort4 lv4 = *(const ushort4*)(lvbuf + base + (size_t)s * D_);
        const unsigned short* lcp = &lc4.x;
        const unsigned short* lvp = &lv4.x;
#pragma unroll
        for (int j = 0; j < 4; ++j) {
            float lc = h2f(lcp[j]), lv = h2f(lvp[j]);
            A[j] += lc;
            lb[j] = logaddexp_f(lb[j] + lc, lv);
        }
    }
    size_t o = ((size_t)b * NC_ + c) * D_ + d;
    *(float4*)(Aagg + o)  = (float4){A[0], A[1], A[2], A[3]};
    *(float4*)(lBagg + o) = (float4){lb[0], lb[1], lb[2], lb[3]};
}

// ---------------------------------------------------------------------------
// Kernel 3: scan across chunks (NC_=64 steps, tiny). P[c] = log h at entry.
// ---------------------------------------------------------------------------
__global__ void chunk_scan(const float* __restrict__ Aagg,
                           const float* __restrict__ lBagg,
                           float* __restrict__ P)
{
    const int d = blockIdx.x * 256 + threadIdx.x;
    const int b = blockIdx.z;
    float p = -INFINITY;
    for (int c = 0; c < NC_; ++c) {
        size_t o = ((size_t)b * NC_ + c) * D_ + d;
        P[o] = p;
        p = logaddexp_f(Aagg[o] + p, lBagg[o]);
    }
}

// ---------------------------------------------------------------------------
// Kernel 4: local scan applying chunk prefix; out = e^(a+p) + e^lb
// ---------------------------------------------------------------------------
__global__ __launch_bounds__(256) void chunk_apply(
    const __half* __restrict__ lcbuf, const __half* __restrict__ lvbuf,
    const float* __restrict__ P, float* __restrict__ out)
{
    const int d = threadIdx.x * 4;
    const int c = blockIdx.y;
    const int b = blockIdx.z;
    size_t base = ((size_t)(b * S_ + c * L_)) * D_ + d;
    float4 p4 = *(const float4*)(P + ((size_t)b * NC_ + c) * D_ + d);
    float p[4] = {p4.x, p4.y, p4.z, p4.w};
    float a[4] = {0.f, 0.f, 0.f, 0.f};
    float lb[4] = {-INFINITY, -INFINITY, -INFINITY, -INFINITY};
    for (int s = 0; s < L_; ++s) {
        ushort4 lc4 = *(const ushort4*)(lcbuf + base + (size_t)s * D_);
        ushort4 lv4 = *(const ushort4*)(lvbuf + base + (size_t)s * D_);
        const unsigned short* lcp = &lc4.x;
        const unsigned short* lvp = &lv4.x;
        float4 o4;
        float* op = &o4.x;
#pragma unroll
        for (int j = 0; j < 4; ++j) {
            float lc = h2f(lcp[j]), lv = h2f(lvp[j]);
            a[j] += lc;
            lb[j] = logaddexp_f(lb[j] + lc, lv);
            op[j] = __expf(a[j] + p[j]) + __expf(lb[j]);
        }
        *(float4*)(out + base + (size_t)s * D_) = o4;
    }
}

extern "C" void kernel_launch(void* const* d_in, const int* in_sizes, int n_in,
                              void* d_out, int out_size, void* d_ws, size_t ws_size,
                              hipStream_t stream) {
    const float* x = (const float*)d_in[0];   // [B,S,D] fp32
    const float* W = (const float*)d_in[1];   // [2D,D] fp32
    float* out = (float*)d_out;               // [B,S,D] fp32

    float* Aagg  = (float*)d_ws;                          // B*NC*D f32
    float* lBagg = Aagg  + (size_t)B_ * NC_ * D_;
    float* P     = lBagg + (size_t)B_ * NC_ * D_;
    __half* lch  = (__half*)(P + (size_t)B_ * NC_ * D_);  // M*D fp16
    __half* lvh  = lch + (size_t)M_ * D_;                 // M*D fp16
    unsigned short* xb = (unsigned short*)(lvh + (size_t)M_ * D_);  // M*K bf16
    unsigned short* Wb = xb + (size_t)M_ * K_;                      // 2D*K bf16

    const int nx8 = M_ * K_ / 8;
    const int nw8 = 2 * D_ * K_ / 8;
    to_bf16<<<(nx8 + 255) / 256, 256, 0, stream>>>(x, xb, nx8);
    to_bf16<<<(nw8 + 255) / 256, 256, 0, stream>>>(W, Wb, nw8);

    dim3 g1(D_ / 64, M_ / 128, 1);        // 16 x 128 blocks
    gemm_pointwise<<<g1, 256, 0, stream>>>(xb, Wb, lch, lvh);

    dim3 g2(1, NC_, B_);                  // 1 x 64 x 4
    chunk_reduce<<<g2, 256, 0, stream>>>(lch, lvh, Aagg, lBagg);

    dim3 g3(D_ / 256, 1, B_);             // 4 x 1 x 4
    chunk_scan<<<g3, 256, 0, stream>>>(Aagg, lBagg, P);

    chunk_apply<<<g2, 256, 0, stream>>>(lch, lvh, P, out);
}

// Round 4
// 180.254 us; speedup vs baseline: 1.1905x; 1.0230x over previous
//
#include <hip/hip_runtime.h>
#include <hip/hip_bf16.h>
#include <hip/hip_fp16.h>
#include <math.h>

#define B_  4
#define S_  4096
#define D_  1024
#define M_  (B_ * S_)   // 16384 rows
#define K_  D_          // 1024 reduction
#define L_  64          // scan chunk length
#define NC_ (S_ / L_)   // 64 chunks per sequence
#define NKT 32          // K_/32 K-tiles

typedef __attribute__((ext_vector_type(8))) short          bf16x8;
typedef __attribute__((ext_vector_type(8))) unsigned short u16x8;
typedef __attribute__((ext_vector_type(4))) float          f32x4;

__device__ __forceinline__ float softplus_f(float x) {
    return fmaxf(x, 0.0f) + __logf(1.0f + __expf(-fabsf(x)));
}

__device__ __forceinline__ unsigned short f2bf(float f) {
    union { __hip_bfloat16 h; unsigned short u; } cv;
    cv.h = __float2bfloat16(f);
    return cv.u;
}

__device__ __forceinline__ float h2f(unsigned short u) {
    union { __half h; unsigned short u; } cv;
    cv.u = u;
    return __half2float(cv.h);
}

__device__ __forceinline__ float logaddexp_f(float u, float v) {
    float m = fmaxf(u, v);
    return m + __logf(1.0f + __expf(-fabsf(u - v)));
}

// ---------------------------------------------------------------------------
// Kernel 0: fp32 -> bf16 pre-convert
// ---------------------------------------------------------------------------
__global__ __launch_bounds__(256) void to_bf16(
    const float* __restrict__ in, unsigned short* __restrict__ out, int n8)
{
    int i = blockIdx.x * 256 + threadIdx.x;
    if (i >= n8) return;
    const float4* p = (const float4*)in + (size_t)i * 2;
    float4 a = p[0], b = p[1];
    u16x8 o;
    o[0] = f2bf(a.x); o[1] = f2bf(a.y); o[2] = f2bf(a.z); o[3] = f2bf(a.w);
    o[4] = f2bf(b.x); o[5] = f2bf(b.y); o[6] = f2bf(b.z); o[7] = f2bf(b.w);
    *(u16x8*)(out + (size_t)i * 8) = o;
}

// ---------------------------------------------------------------------------
// Kernel 1: 256x(128d x {h,g}) bf16 MFMA GEMM, 4-deep LDS pipeline with
// counted vmcnt(8) (never drained in main loop), raw s_barrier, setprio
// around MFMA clusters, XCD-swizzled blocks.
// LDS per K-tile buf (32KB): A[256][32] bf16 (16KB) + B[256][32] (16KB);
// B rows 0-127 = hidden W rows d0.., rows 128-255 = gate W rows 1024+d0..
// Swizzle (round-3-verified involution, 64B rows): 16B-slot ^= (row>>1)&3,
// applied on the global SOURCE (stage) and the ds_read offset (read).
// ---------------------------------------------------------------------------
struct GemmRegs { f32x4 a[8][4]; };

__device__ __forceinline__ void gemm_phases(
    const char* __restrict__ bp, int aoff, int boff, f32x4 (&acc)[8][4])
{
    bf16x8 a4[4], b4[4];
#pragma unroll
    for (int i = 0; i < 4; ++i)
        a4[i] = *(const bf16x8*)(bp + aoff + i * 1024);
#pragma unroll
    for (int j = 0; j < 2; ++j) {
        b4[j]     = *(const bf16x8*)(bp + boff + j * 1024);          // hidden
        b4[j + 2] = *(const bf16x8*)(bp + boff + 8192 + j * 1024);   // gate
    }
    __builtin_amdgcn_s_setprio(1);
#pragma unroll
    for (int i = 0; i < 4; ++i)
#pragma unroll
        for (int j = 0; j < 4; ++j)
            acc[i][j] = __builtin_amdgcn_mfma_f32_16x16x32_bf16(
                a4[i], b4[j], acc[i][j], 0, 0, 0);
    __builtin_amdgcn_s_setprio(0);
#pragma unroll
    for (int i = 0; i < 4; ++i)
        a4[i] = *(const bf16x8*)(bp + aoff + 4096 + i * 1024);   // rows +64
    __builtin_amdgcn_s_setprio(1);
#pragma unroll
    for (int i = 0; i < 4; ++i)
#pragma unroll
        for (int j = 0; j < 4; ++j)
            acc[4 + i][j] = __builtin_amdgcn_mfma_f32_16x16x32_bf16(
                a4[i], b4[j], acc[4 + i][j], 0, 0, 0);
    __builtin_amdgcn_s_setprio(0);
}

__global__ __launch_bounds__(512, 2) void gemm_pointwise(
    const unsigned short* __restrict__ xb, const unsigned short* __restrict__ Wb,
    __half* __restrict__ lcbuf, __half* __restrict__ lvbuf)
{
    __shared__ char lds[131072];   // 4 bufs x (A 16KB + B 16KB)

    const int th   = threadIdx.x;
    const int lane = th & 63;
    const int wave = th >> 6;
    const int wm = wave >> 2;      // 0..1 -> m offset 0/128
    const int wn = wave & 3;       // 0..3 -> d offset 32*wn

    // XCD-bijective swizzle: 512 wgs, 8 XCDs, 64 per XCD chunk
    const int wg  = blockIdx.x;
    const int swz = (wg & 7) * 64 + (wg >> 3);
    const int m0 = (swz >> 3) * 256;
    const int d0 = (swz & 7) * 128;

    f32x4 acc[8][4];
#pragma unroll
    for (int i = 0; i < 8; ++i)
#pragma unroll
        for (int j = 0; j < 4; ++j)
            acc[i][j] = (f32x4){0.f, 0.f, 0.f, 0.f};

    // staging: 512 thr x 16B = 8KB = 128 rows/round; 2 rounds each for A,B
    const int srow = th >> 2;                               // 0..127
    const int scol = (((th & 3) ^ ((th >> 3) & 3)) * 8);    // pre-swizzled src col
    const unsigned short* gA0 = xb + (size_t)(m0 + srow)        * K_ + scol;
    const unsigned short* gA1 = xb + (size_t)(m0 + 128 + srow)  * K_ + scol;
    const unsigned short* gB0 = Wb + (size_t)(d0 + srow)        * K_ + scol;  // hidden
    const unsigned short* gB1 = Wb + (size_t)(D_ + d0 + srow)   * K_ + scol;  // gate
    char* ldsw = lds + wave * 1024;   // wave-uniform dest base (lane x16 is HW-added)

#define STAGE(tt) do {                                                               \
    const int ko = (tt) * 32;                                                        \
    char* dst = ldsw + ((tt) & 3) * 32768;                                           \
    __builtin_amdgcn_global_load_lds(                                                \
        (const __attribute__((address_space(1))) unsigned int*)(gA0 + ko),           \
        (__attribute__((address_space(3))) unsigned int*)(dst),          16, 0, 0);  \
    __builtin_amdgcn_global_load_lds(                                                \
        (const __attribute__((address_space(1))) unsigned int*)(gA1 + ko),           \
        (__attribute__((address_space(3))) unsigned int*)(dst + 8192),   16, 0, 0);  \
    __builtin_amdgcn_global_load_lds(                                                \
        (const __attribute__((address_space(1))) unsigned int*)(gB0 + ko),           \
        (__attribute__((address_space(3))) unsigned int*)(dst + 16384),  16, 0, 0);  \
    __builtin_amdgcn_global_load_lds(                                                \
        (const __attribute__((address_space(1))) unsigned int*)(gB1 + ko),           \
        (__attribute__((address_space(3))) unsigned int*)(dst + 24576),  16, 0, 0);  \
  } while (0)

    const int lr  = lane & 15;
    const int lkb = (((lane >> 4) ^ ((lr >> 1) & 3)) * 16);   // swizzled read slot
    const int aoff = (wm * 128 + lr) * 64 + lkb;
    const int boff = 16384 + (wn * 32 + lr) * 64 + lkb;

    // prologue: fill 3 tiles, wait for tile 0 only (12 outstanding -> 8)
    STAGE(0); STAGE(1); STAGE(2);
    asm volatile("s_waitcnt vmcnt(8)" ::: "memory");
    asm volatile("s_barrier" ::: "memory");

#pragma unroll 1
    for (int t = 0; t < NKT - 3; ++t) {          // t = 0..28
        STAGE(t + 3);
        gemm_phases(lds + (t & 3) * 32768, aoff, boff, acc);
        asm volatile("s_waitcnt vmcnt(8)" ::: "memory");   // tile t+1 landed
        asm volatile("s_barrier" ::: "memory");
    }
    gemm_phases(lds + ((NKT - 3) & 3) * 32768, aoff, boff, acc);   // t=29
    asm volatile("s_waitcnt vmcnt(4)" ::: "memory");
    asm volatile("s_barrier" ::: "memory");
    gemm_phases(lds + ((NKT - 2) & 3) * 32768, aoff, boff, acc);   // t=30
    asm volatile("s_waitcnt vmcnt(0)" ::: "memory");
    asm volatile("s_barrier" ::: "memory");
    gemm_phases(lds + ((NKT - 1) & 3) * 32768, aoff, boff, acc);   // t=31
#undef STAGE

    // epilogue: pointwise transform + fp16 store
    // C/D: col = lane&15 (B-row/d), row = (lane>>4)*4 + reg (A-row/m)
#pragma unroll
    for (int mi = 0; mi < 8; ++mi)
#pragma unroll
        for (int nj = 0; nj < 2; ++nj)
#pragma unroll
            for (int r = 0; r < 4; ++r) {
                int m = m0 + wm * 128 + mi * 16 + ((lane >> 4) << 2) + r;
                int d = d0 + wn * 32 + nj * 16 + lr;
                float h = acc[mi][nj][r];         // hidden
                float g = acc[mi][nj + 2][r];     // gate, same d
                float lc = -softplus_f(g);
                float lgh = (h >= 0.0f) ? __logf(h + 0.5f) : -softplus_f(-h);
                float lv = -softplus_f(-g) + lgh;
                lcbuf[(size_t)m * D_ + d] = __float2half(lc);
                lvbuf[(size_t)m * D_ + d] = __float2half(lv);
            }
}

// ---------------------------------------------------------------------------
// Kernel 2: per-chunk reduce, 4 d-channels/thread. h_out = e^A h_in + e^lb.
// ---------------------------------------------------------------------------
__global__ __launch_bounds__(256) void chunk_reduce(
    const __half* __restrict__ lcbuf, const __half* __restrict__ lvbuf,
    float* __restrict__ Aagg, float* __restrict__ lBagg)
{
    const int d = threadIdx.x * 4;
    const int c = blockIdx.y;
    const int b = blockIdx.z;
    size_t base = ((size_t)(b * S_ + c * L_)) * D_ + d;
    float A[4] = {0.f, 0.f, 0.f, 0.f};
    float lb[4] = {-INFINITY, -INFINITY, -INFINITY, -INFINITY};
    for (int s = 0; s < L_; ++s) {
        ushort4 lc4 = *(const ushort4*)(lcbuf + base + (size_t)s * D_);
        ushort4 lv4 = *(const ushort4*)(lvbuf + base + (size_t)s * D_);
        const unsigned short* lcp = &lc4.x;
        const unsigned short* lvp = &lv4.x;
#pragma unroll
        for (int j = 0; j < 4; ++j) {
            float lc = h2f(lcp[j]), lv = h2f(lvp[j]);
            A[j] += lc;
            lb[j] = logaddexp_f(lb[j] + lc, lv);
        }
    }
    size_t o = ((size_t)b * NC_ + c) * D_ + d;
    *(float4*)(Aagg + o)  = (float4){A[0], A[1], A[2], A[3]};
    *(float4*)(lBagg + o) = (float4){lb[0], lb[1], lb[2], lb[3]};
}

// ---------------------------------------------------------------------------
// Kernel 3: scan across chunks (64 steps, tiny)
// ---------------------------------------------------------------------------
__global__ void chunk_scan(const float* __restrict__ Aagg,
                           const float* __restrict__ lBagg,
                           float* __restrict__ P)
{
    const int d = blockIdx.x * 256 + threadIdx.x;
    const int b = blockIdx.z;
    float p = -INFINITY;
    for (int c = 0; c < NC_; ++c) {
        size_t o = ((size_t)b * NC_ + c) * D_ + d;
        P[o] = p;
        p = logaddexp_f(Aagg[o] + p, lBagg[o]);
    }
}

// ---------------------------------------------------------------------------
// Kernel 4: local scan applying chunk prefix; out = e^(a+p) + e^lb
// ---------------------------------------------------------------------------
__global__ __launch_bounds__(256) void chunk_apply(
    const __half* __restrict__ lcbuf, const __half* __restrict__ lvbuf,
    const float* __restrict__ P, float* __restrict__ out)
{
    const int d = threadIdx.x * 4;
    const int c = blockIdx.y;
    const int b = blockIdx.z;
    size_t base = ((size_t)(b * S_ + c * L_)) * D_ + d;
    float4 p4 = *(const float4*)(P + ((size_t)b * NC_ + c) * D_ + d);
    float p[4] = {p4.x, p4.y, p4.z, p4.w};
    float a[4] = {0.f, 0.f, 0.f, 0.f};
    float lb[4] = {-INFINITY, -INFINITY, -INFINITY, -INFINITY};
    for (int s = 0; s < L_; ++s) {
        ushort4 lc4 = *(const ushort4*)(lcbuf + base + (size_t)s * D_);
        ushort4 lv4 = *(const ushort4*)(lvbuf + base + (size_t)s * D_);
        const unsigned short* lcp = &lc4.x;
        const unsigned short* lvp = &lv4.x;
        float4 o4;
        float* op = &o4.x;
#pragma unroll
        for (int j = 0; j < 4; ++j) {
            float lc = h2f(lcp[j]), lv = h2f(lvp[j]);
            a[j] += lc;
            lb[j] = logaddexp_f(lb[j] + lc, lv);
            op[j] = __expf(a[j] + p[j]) + __expf(lb[j]);
        }
        *(float4*)(out + base + (size_t)s * D_) = o4;
    }
}

extern "C" void kernel_launch(void* const* d_in, const int* in_sizes, int n_in,
                              void* d_out, int out_size, void* d_ws, size_t ws_size,
                              hipStream_t stream) {
    const float* x = (const float*)d_in[0];   // [B,S,D] fp32
    const float* W = (const float*)d_in[1];   // [2D,D] fp32
    float* out = (float*)d_out;               // [B,S,D] fp32

    float* Aagg  = (float*)d_ws;                          // B*NC*D f32
    float* lBagg = Aagg  + (size_t)B_ * NC_ * D_;
    float* P     = lBagg + (size_t)B_ * NC_ * D_;
    __half* lch  = (__half*)(P + (size_t)B_ * NC_ * D_);  // M*D fp16
    __half* lvh  = lch + (size_t)M_ * D_;                 // M*D fp16
    unsigned short* xb = (unsigned short*)(lvh + (size_t)M_ * D_);  // M*K bf16
    unsigned short* Wb = xb + (size_t)M_ * K_;                      // 2D*K bf16

    const int nx8 = M_ * K_ / 8;
    const int nw8 = 2 * D_ * K_ / 8;
    to_bf16<<<(nx8 + 255) / 256, 256, 0, stream>>>(x, xb, nx8);
    to_bf16<<<(nw8 + 255) / 256, 256, 0, stream>>>(W, Wb, nw8);

    // 512 wgs: (M/256)=64 m-tiles x (D/128)=8 d-tiles, XCD-swizzled in-kernel
    gemm_pointwise<<<512, 512, 0, stream>>>(xb, Wb, lch, lvh);

    dim3 g2(1, NC_, B_);
    chunk_reduce<<<g2, 256, 0, stream>>>(lch, lvh, Aagg, lBagg);

    dim3 g3(D_ / 256, 1, B_);
    chunk_scan<<<g3, 256, 0, stream>>>(Aagg, lBagg, P);

    chunk_apply<<<g2, 256, 0, stream>>>(lch, lvh, P, out);
}

// Round 5
// 179.781 us; speedup vs baseline: 1.1936x; 1.0026x over previous
//
#include <hip/hip_runtime.h>
#include <hip/hip_bf16.h>
#include <hip/hip_fp16.h>
#include <math.h>

#define B_  4
#define S_  4096
#define D_  1024
#define M_  (B_ * S_)   // 16384 rows
#define K_  D_          // 1024 reduction
#define L_  64          // scan chunk length
#define NC_ (S_ / L_)   // 64 chunks per sequence
#define NKT 16          // K_/64 K-tiles (BK=64)

typedef __attribute__((ext_vector_type(8))) short          bf16x8;
typedef __attribute__((ext_vector_type(8))) unsigned short u16x8;
typedef __attribute__((ext_vector_type(4))) float          f32x4;

__device__ __forceinline__ float softplus_f(float x) {
    return fmaxf(x, 0.0f) + __logf(1.0f + __expf(-fabsf(x)));
}

__device__ __forceinline__ unsigned short f2bf(float f) {
    union { __hip_bfloat16 h; unsigned short u; } cv;
    cv.h = __float2bfloat16(f);
    return cv.u;
}

__device__ __forceinline__ float h2f(unsigned short u) {
    union { __half h; unsigned short u; } cv;
    cv.u = u;
    return __half2float(cv.h);
}

__device__ __forceinline__ float logaddexp_f(float u, float v) {
    float m = fmaxf(u, v);
    return m + __logf(1.0f + __expf(-fabsf(u - v)));
}

__device__ __forceinline__ void stage16(const unsigned short* src, char* dst) {
    __builtin_amdgcn_global_load_lds(
        (const __attribute__((address_space(1))) unsigned int*)src,
        (__attribute__((address_space(3))) unsigned int*)dst, 16, 0, 0);
}

// ---------------------------------------------------------------------------
// Kernel 0: fp32 -> bf16 pre-convert
// ---------------------------------------------------------------------------
__global__ __launch_bounds__(256) void to_bf16(
    const float* __restrict__ in, unsigned short* __restrict__ out, int n8)
{
    int i = blockIdx.x * 256 + threadIdx.x;
    if (i >= n8) return;
    const float4* p = (const float4*)in + (size_t)i * 2;
    float4 a = p[0], b = p[1];
    u16x8 o;
    o[0] = f2bf(a.x); o[1] = f2bf(a.y); o[2] = f2bf(a.z); o[3] = f2bf(a.w);
    o[4] = f2bf(b.x); o[5] = f2bf(b.y); o[6] = f2bf(b.z); o[7] = f2bf(b.w);
    *(u16x8*)(out + (size_t)i * 8) = o;
}

// ---------------------------------------------------------------------------
// Kernel 1: 8-phase-template bf16 MFMA GEMM (m201 port), fused pointwise.
// BM=256, BN=128d x {h,g} = 256 cols, BK=64, 8 waves (2M x 4N), 2-deep LDS.
// Buf layout (64KB each): [A k0 16K | A k1 16K | B k0 16K | B k1 16K];
// B rows: 128 hidden then 128 gate. Rows are 64B (32 bf16), slot-swizzled
// with the round-3-verified involution (slot ^= (row>>1)&3 on BOTH sides).
// Per K-tile: 4 phases, each {read next frags, stage, bar, lgkmcnt(0),
// 16 MFMA w/setprio, bar}; single vmcnt(0) at phase 3 (loads ~2 phases old).
// ---------------------------------------------------------------------------
__global__ __launch_bounds__(512, 2) void gemm_pointwise(
    const unsigned short* __restrict__ xb, const unsigned short* __restrict__ Wb,
    __half* __restrict__ lcbuf, __half* __restrict__ lvbuf)
{
    __shared__ char lds[131072];   // 2 x 64KB

    const int th   = threadIdx.x;
    const int lane = th & 63;
    const int wave = th >> 6;
    const int wm = wave >> 2;      // 0..1 -> m offset 0/128
    const int wn = wave & 3;       // 0..3 -> d offset 32*wn

    const int wg  = blockIdx.x;                    // 512 wgs, 8 XCDs
    const int swz = (wg & 7) * 64 + (wg >> 3);     // bijective XCD swizzle
    const int m0 = (swz >> 3) * 256;
    const int d0 = (swz & 7) * 128;

    f32x4 acc[8][4];
#pragma unroll
    for (int i = 0; i < 8; ++i)
#pragma unroll
        for (int j = 0; j < 4; ++j)
            acc[i][j] = (f32x4){0.f, 0.f, 0.f, 0.f};

    // staging: 512 thr x 16B = 8KB = 128 rows per round; 8 rounds per K-tile
    const int srow = th >> 2;                               // 0..127
    const int scol = (((th & 3) ^ ((th >> 3) & 3)) * 8);    // pre-swizzled col
    const unsigned short* srcA  = xb + (size_t)(m0 + srow)       * K_ + scol;
    const unsigned short* srcA2 = xb + (size_t)(m0 + 128 + srow) * K_ + scol;
    const unsigned short* srcBh = Wb + (size_t)(d0 + srow)       * K_ + scol;
    const unsigned short* srcBg = Wb + (size_t)(D_ + d0 + srow)  * K_ + scol;
    char* const wuo = lds + wave * 1024;   // wave-uniform LDS dest base

    const int lr  = lane & 15;
    const int lkb = (((lane >> 4) ^ ((lr >> 1) & 3)) * 16);   // swizzled slot
    const int aoffb = (wm * 128 + lr) * 64 + lkb;             // A frag base
    const int boffb = 32768 + (wn * 32 + lr) * 64 + lkb;      // B frag base

    bf16x8 Aa[4], Ab[4], Ba[4], Bb[4];

#define BAR()  asm volatile("s_barrier" ::: "memory")
#define LGK0() asm volatile("s_waitcnt lgkmcnt(0)" ::: "memory")
#define VM0()  asm volatile("s_waitcnt vmcnt(0)" ::: "memory")

#define CLUSTER(base, AF, BF) do {                                        \
    __builtin_amdgcn_s_setprio(1);                                        \
    _Pragma("unroll")                                                     \
    for (int i_ = 0; i_ < 4; ++i_)                                        \
        _Pragma("unroll")                                                 \
        for (int j_ = 0; j_ < 4; ++j_)                                    \
            acc[(base) + i_][j_] = __builtin_amdgcn_mfma_f32_16x16x32_bf16(\
                AF[i_], BF[j_], acc[(base) + i_][j_], 0, 0, 0);           \
    __builtin_amdgcn_s_setprio(0);                                        \
  } while (0)

    // prologue: stage tile 0 (all 8 rounds) into buf0, drain, read phase-0 frags
    stage16(srcA,       wuo + 0);
    stage16(srcA2,      wuo + 8192);
    stage16(srcA  + 32, wuo + 16384);
    stage16(srcA2 + 32, wuo + 24576);
    stage16(srcBh,      wuo + 32768);
    stage16(srcBg,      wuo + 40960);
    stage16(srcBh + 32, wuo + 49152);
    stage16(srcBg + 32, wuo + 57344);
    VM0();
    BAR();
    {
        const char* bc = lds;
#pragma unroll
        for (int i = 0; i < 4; ++i)
            Aa[i] = *(const bf16x8*)(bc + aoffb + i * 1024);
#pragma unroll
        for (int j = 0; j < 2; ++j) {
            Ba[j]     = *(const bf16x8*)(bc + boffb + j * 1024);
            Ba[j + 2] = *(const bf16x8*)(bc + boffb + 8192 + j * 1024);
        }
    }

#pragma unroll 1
    for (int t = 0; t < NKT; ++t) {
        const char* bc  = lds + (t & 1) * 65536;        // compute buf (read)
        char*       bn  = wuo + ((t + 1) & 1) * 65536;  // next buf (stage dest)
        const char* bnr = lds + ((t + 1) & 1) * 65536;  // next buf (read)
        const int kof = (t + 1) * 64;
        const bool pre = (t < NKT - 1);

        // ---- phase 0: MFMA acc[0..3] = A(mh0,k0) x B(k0) ----
#pragma unroll
        for (int i = 0; i < 4; ++i)
            Ab[i] = *(const bf16x8*)(bc + aoffb + 4096 + i * 1024);    // (mh1,k0)
        if (pre) {
            stage16(srcA  + kof,      bn + 0);
            stage16(srcA2 + kof,      bn + 8192);
            stage16(srcA  + kof + 32, bn + 16384);
            stage16(srcA2 + kof + 32, bn + 24576);
        }
        BAR(); LGK0();
        CLUSTER(0, Aa, Ba);
        BAR();

        // ---- phase 1: MFMA acc[4..7] = A(mh1,k0) x B(k0) ----
#pragma unroll
        for (int i = 0; i < 4; ++i)
            Aa[i] = *(const bf16x8*)(bc + aoffb + 16384 + i * 1024);   // (mh0,k1)
#pragma unroll
        for (int j = 0; j < 2; ++j) {
            Bb[j]     = *(const bf16x8*)(bc + boffb + 16384 + j * 1024);         // B(k1) h
            Bb[j + 2] = *(const bf16x8*)(bc + boffb + 16384 + 8192 + j * 1024);  // B(k1) g
        }
        if (pre) {
            stage16(srcBh + kof,      bn + 32768);
            stage16(srcBg + kof,      bn + 40960);
            stage16(srcBh + kof + 32, bn + 49152);
            stage16(srcBg + kof + 32, bn + 57344);
        }
        BAR(); LGK0();
        CLUSTER(4, Ab, Ba);
        BAR();

        // ---- phase 2: MFMA acc[0..3] = A(mh0,k1) x B(k1) ----
#pragma unroll
        for (int i = 0; i < 4; ++i)
            Ab[i] = *(const bf16x8*)(bc + aoffb + 4096 + 16384 + i * 1024);  // (mh1,k1)
        BAR(); LGK0();
        CLUSTER(0, Aa, Bb);
        BAR();

        // ---- phase 3: MFMA acc[4..7] = A(mh1,k1) x B(k1); cross-buf sync ----
        VM0();           // t+1's 8 loads issued >=2 phases ago -> free drain
        BAR();           // after this, buf[(t+1)&1] globally valid
        CLUSTER(4, Ab, Bb);
        if (pre) {       // prefetch next tile's phase-0 frags
#pragma unroll
            for (int i = 0; i < 4; ++i)
                Aa[i] = *(const bf16x8*)(bnr + aoffb + i * 1024);
#pragma unroll
            for (int j = 0; j < 2; ++j) {
                Ba[j]     = *(const bf16x8*)(bnr + boffb + j * 1024);
                Ba[j + 2] = *(const bf16x8*)(bnr + boffb + 8192 + j * 1024);
            }
        }
        BAR();
    }
#undef CLUSTER
#undef BAR
#undef LGK0
#undef VM0

    // epilogue: pointwise transform + fp16 store
    // C/D: col = lane&15 (B-row/d), row = (lane>>4)*4 + reg (A-row/m)
#pragma unroll
    for (int mi = 0; mi < 8; ++mi)
#pragma unroll
        for (int nj = 0; nj < 2; ++nj)
#pragma unroll
            for (int r = 0; r < 4; ++r) {
                int m = m0 + wm * 128 + mi * 16 + ((lane >> 4) << 2) + r;
                int d = d0 + wn * 32 + nj * 16 + lr;
                float h = acc[mi][nj][r];         // hidden
                float g = acc[mi][nj + 2][r];     // gate, same d
                float lc = -softplus_f(g);
                float lgh = (h >= 0.0f) ? __logf(h + 0.5f) : -softplus_f(-h);
                float lv = -softplus_f(-g) + lgh;
                lcbuf[(size_t)m * D_ + d] = __float2half(lc);
                lvbuf[(size_t)m * D_ + d] = __float2half(lv);
            }
}

// ---------------------------------------------------------------------------
// Kernel 2: per-chunk reduce, 4 d-channels/thread. h_out = e^A h_in + e^lb.
// ---------------------------------------------------------------------------
__global__ __launch_bounds__(256) void chunk_reduce(
    const __half* __restrict__ lcbuf, const __half* __restrict__ lvbuf,
    float* __restrict__ Aagg, float* __restrict__ lBagg)
{
    const int d = threadIdx.x * 4;
    const int c = blockIdx.y;
    const int b = blockIdx.z;
    size_t base = ((size_t)(b * S_ + c * L_)) * D_ + d;
    float A[4] = {0.f, 0.f, 0.f, 0.f};
    float lb[4] = {-INFINITY, -INFINITY, -INFINITY, -INFINITY};
    for (int s = 0; s < L_; ++s) {
        ushort4 lc4 = *(const ushort4*)(lcbuf + base + (size_t)s * D_);
        ushort4 lv4 = *(const ushort4*)(lvbuf + base + (size_t)s * D_);
        const unsigned short* lcp = &lc4.x;
        const unsigned short* lvp = &lv4.x;
#pragma unroll
        for (int j = 0; j < 4; ++j) {
            float lc = h2f(lcp[j]), lv = h2f(lvp[j]);
            A[j] += lc;
            lb[j] = logaddexp_f(lb[j] + lc, lv);
        }
    }
    size_t o = ((size_t)b * NC_ + c) * D_ + d;
    *(float4*)(Aagg + o)  = (float4){A[0], A[1], A[2], A[3]};
    *(float4*)(lBagg + o) = (float4){lb[0], lb[1], lb[2], lb[3]};
}

// ---------------------------------------------------------------------------
// Kernel 3: scan across chunks (64 steps, tiny)
// ---------------------------------------------------------------------------
__global__ void chunk_scan(const float* __restrict__ Aagg,
                           const float* __restrict__ lBagg,
                           float* __restrict__ P)
{
    const int d = blockIdx.x * 256 + threadIdx.x;
    const int b = blockIdx.z;
    float p = -INFINITY;
    for (int c = 0; c < NC_; ++c) {
        size_t o = ((size_t)b * NC_ + c) * D_ + d;
        P[o] = p;
        p = logaddexp_f(Aagg[o] + p, lBagg[o]);
    }
}

// ---------------------------------------------------------------------------
// Kernel 4: local scan applying chunk prefix; out = e^(a+p) + e^lb
// ---------------------------------------------------------------------------
__global__ __launch_bounds__(256) void chunk_apply(
    const __half* __restrict__ lcbuf, const __half* __restrict__ lvbuf,
    const float* __restrict__ P, float* __restrict__ out)
{
    const int d = threadIdx.x * 4;
    const int c = blockIdx.y;
    const int b = blockIdx.z;
    size_t base = ((size_t)(b * S_ + c * L_)) * D_ + d;
    float4 p4 = *(const float4*)(P + ((size_t)b * NC_ + c) * D_ + d);
    float p[4] = {p4.x, p4.y, p4.z, p4.w};
    float a[4] = {0.f, 0.f, 0.f, 0.f};
    float lb[4] = {-INFINITY, -INFINITY, -INFINITY, -INFINITY};
    for (int s = 0; s < L_; ++s) {
        ushort4 lc4 = *(const ushort4*)(lcbuf + base + (size_t)s * D_);
        ushort4 lv4 = *(const ushort4*)(lvbuf + base + (size_t)s * D_);
        const unsigned short* lcp = &lc4.x;
        const unsigned short* lvp = &lv4.x;
        float4 o4;
        float* op = &o4.x;
#pragma unroll
        for (int j = 0; j < 4; ++j) {
            float lc = h2f(lcp[j]), lv = h2f(lvp[j]);
            a[j] += lc;
            lb[j] = logaddexp_f(lb[j] + lc, lv);
            op[j] = __expf(a[j] + p[j]) + __expf(lb[j]);
        }
        *(float4*)(out + base + (size_t)s * D_) = o4;
    }
}

extern "C" void kernel_launch(void* const* d_in, const int* in_sizes, int n_in,
                              void* d_out, int out_size, void* d_ws, size_t ws_size,
                              hipStream_t stream) {
    const float* x = (const float*)d_in[0];   // [B,S,D] fp32
    const float* W = (const float*)d_in[1];   // [2D,D] fp32
    float* out = (float*)d_out;               // [B,S,D] fp32

    float* Aagg  = (float*)d_ws;                          // B*NC*D f32
    float* lBagg = Aagg  + (size_t)B_ * NC_ * D_;
    float* P     = lBagg + (size_t)B_ * NC_ * D_;
    __half* lch  = (__half*)(P + (size_t)B_ * NC_ * D_);  // M*D fp16
    __half* lvh  = lch + (size_t)M_ * D_;                 // M*D fp16
    unsigned short* xb = (unsigned short*)(lvh + (size_t)M_ * D_);  // M*K bf16
    unsigned short* Wb = xb + (size_t)M_ * K_;                      // 2D*K bf16

    const int nx8 = M_ * K_ / 8;
    const int nw8 = 2 * D_ * K_ / 8;
    to_bf16<<<(nx8 + 255) / 256, 256, 0, stream>>>(x, xb, nx8);
    to_bf16<<<(nw8 + 255) / 256, 256, 0, stream>>>(W, Wb, nw8);

    // 512 wgs: 64 m-tiles x 8 d-tiles, XCD-swizzled in-kernel
    gemm_pointwise<<<512, 512, 0, stream>>>(xb, Wb, lch, lvh);

    dim3 g2(1, NC_, B_);
    chunk_reduce<<<g2, 256, 0, stream>>>(lch, lvh, Aagg, lBagg);

    dim3 g3(D_ / 256, 1, B_);
    chunk_scan<<<g3, 256, 0, stream>>>(Aagg, lBagg, P);

    chunk_apply<<<g2, 256, 0, stream>>>(lch, lvh, P, out);
}

// Round 6
// 135.151 us; speedup vs baseline: 1.5878x; 1.3302x over previous
//
#include <hip/hip_runtime.h>
#include <hip/hip_bf16.h>
#include <hip/hip_fp16.h>
#include <math.h>

#define B_  4
#define S_  4096
#define D_  1024
#define M_  (B_ * S_)   // 16384 rows
#define K_  D_          // 1024 reduction
#define L_  32          // scan chunk length
#define NC_ (S_ / L_)   // 128 chunks per sequence
#define NKT 16          // K_/64 K-tiles (BK=64)

typedef __attribute__((ext_vector_type(8))) short          bf16x8;
typedef __attribute__((ext_vector_type(8))) unsigned short u16x8;
typedef __attribute__((ext_vector_type(4))) float          f32x4;

__device__ __forceinline__ unsigned short f2bf(float f) {
    union { __hip_bfloat16 h; unsigned short u; } cv;
    cv.h = __float2bfloat16(f);
    return cv.u;
}

__device__ __forceinline__ float fast_rcp(float x) {
#if __has_builtin(__builtin_amdgcn_rcpf)
    return __builtin_amdgcn_rcpf(x);
#else
    return 1.0f / x;
#endif
}

__device__ __forceinline__ void stage16(const unsigned short* src, char* dst) {
    __builtin_amdgcn_global_load_lds(
        (const __attribute__((address_space(1))) unsigned int*)src,
        (__attribute__((address_space(3))) unsigned int*)dst, 16, 0, 0);
}

// ---------------------------------------------------------------------------
// Kernel 0: fp32 -> bf16 pre-convert
// ---------------------------------------------------------------------------
__global__ __launch_bounds__(256) void to_bf16(
    const float* __restrict__ in, unsigned short* __restrict__ out, int n8)
{
    int i = blockIdx.x * 256 + threadIdx.x;
    if (i >= n8) return;
    const float4* p = (const float4*)in + (size_t)i * 2;
    float4 a = p[0], b = p[1];
    u16x8 o;
    o[0] = f2bf(a.x); o[1] = f2bf(a.y); o[2] = f2bf(a.z); o[3] = f2bf(a.w);
    o[4] = f2bf(b.x); o[5] = f2bf(b.y); o[6] = f2bf(b.z); o[7] = f2bf(b.w);
    *(u16x8*)(out + (size_t)i * 8) = o;
}

// ---------------------------------------------------------------------------
// Kernel 1: bf16 MFMA GEMM (8-phase, 2-deep LDS, counted waits) fused with
// the LINEAR-domain pointwise epilogue:
//   c = sigma(-g) = 1/(1+e^g)   (recurrence coefficient, in (0,1))
//   v = sigma(g) * g(h),  g(h) = h>=0 ? h+0.5 : sigma(h)
// packed as __half2(c,v) -> one 4B store per output.
// BM=256, BN=128d x {h,g}, BK=64, 8 waves (2M x 4N). Swizzle involution
// (slot ^= (row>>1)&3) applied on BOTH stage-source and read (rule #21).
// ---------------------------------------------------------------------------
__global__ __launch_bounds__(512, 2) void gemm_pointwise(
    const unsigned short* __restrict__ xb, const unsigned short* __restrict__ Wb,
    __half2* __restrict__ cvb)
{
    __shared__ char lds[131072];   // 2 x 64KB

    const int th   = threadIdx.x;
    const int lane = th & 63;
    const int wave = th >> 6;
    const int wm = wave >> 2;      // 0..1 -> m offset 0/128
    const int wn = wave & 3;       // 0..3 -> d offset 32*wn

    const int wg  = blockIdx.x;                    // 512 wgs, 8 XCDs
    const int swz = (wg & 7) * 64 + (wg >> 3);     // bijective XCD swizzle
    const int m0 = (swz >> 3) * 256;
    const int d0 = (swz & 7) * 128;

    f32x4 acc[8][4];
#pragma unroll
    for (int i = 0; i < 8; ++i)
#pragma unroll
        for (int j = 0; j < 4; ++j)
            acc[i][j] = (f32x4){0.f, 0.f, 0.f, 0.f};

    // staging: 512 thr x 16B = 8KB = 128 rows per round; 8 rounds per K-tile
    const int srow = th >> 2;                               // 0..127
    const int scol = (((th & 3) ^ ((th >> 3) & 3)) * 8);    // pre-swizzled col
    const unsigned short* srcA  = xb + (size_t)(m0 + srow)       * K_ + scol;
    const unsigned short* srcA2 = xb + (size_t)(m0 + 128 + srow) * K_ + scol;
    const unsigned short* srcBh = Wb + (size_t)(d0 + srow)       * K_ + scol;
    const unsigned short* srcBg = Wb + (size_t)(D_ + d0 + srow)  * K_ + scol;
    char* const wuo = lds + wave * 1024;   // wave-uniform LDS dest base

    const int lr  = lane & 15;
    const int lkb = (((lane >> 4) ^ ((lr >> 1) & 3)) * 16);   // swizzled slot
    const int aoffb = (wm * 128 + lr) * 64 + lkb;             // A frag base
    const int boffb = 32768 + (wn * 32 + lr) * 64 + lkb;      // B frag base

    bf16x8 Aa[4], Ab[4], Ba[4], Bb[4];

#define BAR()  asm volatile("s_barrier" ::: "memory")
#define LGK0() asm volatile("s_waitcnt lgkmcnt(0)" ::: "memory")
#define VM0()  asm volatile("s_waitcnt vmcnt(0)" ::: "memory")

#define CLUSTER(base, AF, BF) do {                                        \
    __builtin_amdgcn_s_setprio(1);                                        \
    _Pragma("unroll")                                                     \
    for (int i_ = 0; i_ < 4; ++i_)                                        \
        _Pragma("unroll")                                                 \
        for (int j_ = 0; j_ < 4; ++j_)                                    \
            acc[(base) + i_][j_] = __builtin_amdgcn_mfma_f32_16x16x32_bf16(\
                AF[i_], BF[j_], acc[(base) + i_][j_], 0, 0, 0);           \
    __builtin_amdgcn_s_setprio(0);                                        \
  } while (0)

    // prologue: stage tile 0 into buf0, drain, read phase-0 frags
    stage16(srcA,       wuo + 0);
    stage16(srcA2,      wuo + 8192);
    stage16(srcA  + 32, wuo + 16384);
    stage16(srcA2 + 32, wuo + 24576);
    stage16(srcBh,      wuo + 32768);
    stage16(srcBg,      wuo + 40960);
    stage16(srcBh + 32, wuo + 49152);
    stage16(srcBg + 32, wuo + 57344);
    VM0();
    BAR();
    {
        const char* bc = lds;
#pragma unroll
        for (int i = 0; i < 4; ++i)
            Aa[i] = *(const bf16x8*)(bc + aoffb + i * 1024);
#pragma unroll
        for (int j = 0; j < 2; ++j) {
            Ba[j]     = *(const bf16x8*)(bc + boffb + j * 1024);
            Ba[j + 2] = *(const bf16x8*)(bc + boffb + 8192 + j * 1024);
        }
    }

#pragma unroll 1
    for (int t = 0; t < NKT; ++t) {
        const char* bc  = lds + (t & 1) * 65536;        // compute buf (read)
        char*       bn  = wuo + ((t + 1) & 1) * 65536;  // next buf (stage dest)
        const char* bnr = lds + ((t + 1) & 1) * 65536;  // next buf (read)
        const int kof = (t + 1) * 64;
        const bool pre = (t < NKT - 1);

        // ---- phase 0: MFMA acc[0..3] = A(mh0,k0) x B(k0) ----
#pragma unroll
        for (int i = 0; i < 4; ++i)
            Ab[i] = *(const bf16x8*)(bc + aoffb + 4096 + i * 1024);    // (mh1,k0)
        if (pre) {
            stage16(srcA  + kof,      bn + 0);
            stage16(srcA2 + kof,      bn + 8192);
            stage16(srcA  + kof + 32, bn + 16384);
            stage16(srcA2 + kof + 32, bn + 24576);
        }
        BAR(); LGK0();
        CLUSTER(0, Aa, Ba);
        BAR();

        // ---- phase 1: MFMA acc[4..7] = A(mh1,k0) x B(k0) ----
#pragma unroll
        for (int i = 0; i < 4; ++i)
            Aa[i] = *(const bf16x8*)(bc + aoffb + 16384 + i * 1024);   // (mh0,k1)
#pragma unroll
        for (int j = 0; j < 2; ++j) {
            Bb[j]     = *(const bf16x8*)(bc + boffb + 16384 + j * 1024);         // B(k1) h
            Bb[j + 2] = *(const bf16x8*)(bc + boffb + 16384 + 8192 + j * 1024);  // B(k1) g
        }
        if (pre) {
            stage16(srcBh + kof,      bn + 32768);
            stage16(srcBg + kof,      bn + 40960);
            stage16(srcBh + kof + 32, bn + 49152);
            stage16(srcBg + kof + 32, bn + 57344);
        }
        BAR(); LGK0();
        CLUSTER(4, Ab, Ba);
        BAR();

        // ---- phase 2: MFMA acc[0..3] = A(mh0,k1) x B(k1) ----
#pragma unroll
        for (int i = 0; i < 4; ++i)
            Ab[i] = *(const bf16x8*)(bc + aoffb + 4096 + 16384 + i * 1024);  // (mh1,k1)
        BAR(); LGK0();
        CLUSTER(0, Aa, Bb);
        BAR();

        // ---- phase 3: cross-buf sync, prefetch next frags, last cluster ----
        VM0();           // t+1's 8 loads issued >=2 phases ago -> cheap drain
        BAR();           // buf[(t+1)&1] now globally valid
        if (pre) {       // issue next tile's phase-0 frag reads BEFORE MFMAs
#pragma unroll
            for (int i = 0; i < 4; ++i)
                Aa[i] = *(const bf16x8*)(bnr + aoffb + i * 1024);
#pragma unroll
            for (int j = 0; j < 2; ++j) {
                Ba[j]     = *(const bf16x8*)(bnr + boffb + j * 1024);
                Ba[j + 2] = *(const bf16x8*)(bnr + boffb + 8192 + j * 1024);
            }
        }
        CLUSTER(4, Ab, Bb);
        // no trailing barrier: next phase-0 stages into buf[t&1], which no
        // wave reads after phase 2's closing barrier (phase 3 = regs + bnr)
    }
#undef CLUSTER
#undef BAR
#undef LGK0
#undef VM0

    // epilogue: linear-domain pointwise + packed half2 store
    // C/D: col = lane&15 (d), row = (lane>>4)*4 + reg (m)
#pragma unroll
    for (int mi = 0; mi < 8; ++mi)
#pragma unroll
        for (int nj = 0; nj < 2; ++nj)
#pragma unroll
            for (int r = 0; r < 4; ++r) {
                int m = m0 + wm * 128 + mi * 16 + ((lane >> 4) << 2) + r;
                int d = d0 + wn * 32 + nj * 16 + lr;
                float h = acc[mi][nj][r];         // hidden
                float g = acc[mi][nj + 2][r];     // gate, same d
                float eg  = __expf(g);            // |g| <= ~8 -> safe
                float c   = fast_rcp(1.0f + eg);  // sigma(-g) = 1 - z
                float z   = eg * c;               // sigma(g)
                float enh = __expf(-h);
                float sh  = fast_rcp(1.0f + enh); // sigma(h)
                float gh  = (h >= 0.0f) ? (h + 0.5f) : sh;
                float v   = z * gh;
                cvb[(size_t)m * D_ + d] = __floats2half2_rn(c, v);
            }
}

// ---------------------------------------------------------------------------
// Kernel 2: per-chunk reduce (linear domain, pure FMA).
// Chunk map: h_out = C * h_in + V;  C = prod c_t, V = fold fma.
// 2 d-channels per thread, 8B loads.
// ---------------------------------------------------------------------------
__global__ __launch_bounds__(256) void chunk_reduce(
    const unsigned int* __restrict__ cvw,   // half2(c,v) as u32, [m][d]
    float2* __restrict__ CVagg)             // [b][c][d] (C,V)
{
    const int d = (blockIdx.x * 256 + threadIdx.x) * 2;
    const int c = blockIdx.y;
    const int b = blockIdx.z;
    size_t base = ((size_t)(b * S_ + c * L_)) * D_ + d;
    float C0 = 1.f, V0 = 0.f, C1 = 1.f, V1 = 0.f;
    for (int s = 0; s < L_; ++s) {
        uint2 u = *(const uint2*)(cvw + base + (size_t)s * D_);
        float2 p0 = __half22float2(*(const __half2*)&u.x);
        float2 p1 = __half22float2(*(const __half2*)&u.y);
        V0 = fmaf(p0.x, V0, p0.y);  C0 *= p0.x;
        V1 = fmaf(p1.x, V1, p1.y);  C1 *= p1.x;
    }
    size_t o = ((size_t)b * NC_ + c) * D_ + d;
    float4 st = {C0, V0, C1, V1};
    *(float4*)(CVagg + o) = st;   // two adjacent float2, 16B aligned (d even)
}

// ---------------------------------------------------------------------------
// Kernel 3: scan across chunks (128 FMA steps, tiny). P[c] = h at chunk entry.
// ---------------------------------------------------------------------------
__global__ __launch_bounds__(256) void chunk_scan(
    const float2* __restrict__ CVagg, float* __restrict__ P)
{
    const int d = blockIdx.x * 256 + threadIdx.x;
    const int b = blockIdx.z;
    float h = 0.0f;
    for (int c = 0; c < NC_; ++c) {
        size_t o = ((size_t)b * NC_ + c) * D_ + d;
        P[o] = h;
        float2 cv = CVagg[o];
        h = fmaf(cv.x, h, cv.y);
    }
}

// ---------------------------------------------------------------------------
// Kernel 4: apply — h = fma(c, h, v) from chunk-entry prefix; write fp32 out.
// ---------------------------------------------------------------------------
__global__ __launch_bounds__(256) void chunk_apply(
    const unsigned int* __restrict__ cvw, const float* __restrict__ P,
    float* __restrict__ out)
{
    const int d = (blockIdx.x * 256 + threadIdx.x) * 2;
    const int c = blockIdx.y;
    const int b = blockIdx.z;
    size_t base = ((size_t)(b * S_ + c * L_)) * D_ + d;
    float2 h2 = *(const float2*)(P + ((size_t)b * NC_ + c) * D_ + d);
    float h0 = h2.x, h1 = h2.y;
    for (int s = 0; s < L_; ++s) {
        uint2 u = *(const uint2*)(cvw + base + (size_t)s * D_);
        float2 p0 = __half22float2(*(const __half2*)&u.x);
        float2 p1 = __half22float2(*(const __half2*)&u.y);
        h0 = fmaf(p0.x, h0, p0.y);
        h1 = fmaf(p1.x, h1, p1.y);
        float2 o2 = {h0, h1};
        *(float2*)(out + base + (size_t)s * D_) = o2;
    }
}

extern "C" void kernel_launch(void* const* d_in, const int* in_sizes, int n_in,
                              void* d_out, int out_size, void* d_ws, size_t ws_size,
                              hipStream_t stream) {
    const float* x = (const float*)d_in[0];   // [B,S,D] fp32
    const float* W = (const float*)d_in[1];   // [2D,D] fp32
    float* out = (float*)d_out;               // [B,S,D] fp32

    float2* CVagg = (float2*)d_ws;                         // B*NC*D float2 (4MB)
    float*  P     = (float*)(CVagg + (size_t)B_ * NC_ * D_);   // 2MB
    __half2* cvb  = (__half2*)(P + (size_t)B_ * NC_ * D_);     // M*D half2 (64MB)
    unsigned short* xb = (unsigned short*)(cvb + (size_t)M_ * D_);  // 32MB
    unsigned short* Wb = xb + (size_t)M_ * K_;                      // 4MB

    const int nx8 = M_ * K_ / 8;
    const int nw8 = 2 * D_ * K_ / 8;
    to_bf16<<<(nx8 + 255) / 256, 256, 0, stream>>>(x, xb, nx8);
    to_bf16<<<(nw8 + 255) / 256, 256, 0, stream>>>(W, Wb, nw8);

    // 512 wgs: 64 m-tiles x 8 d-tiles, XCD-swizzled in-kernel
    gemm_pointwise<<<512, 512, 0, stream>>>(xb, Wb, cvb);

    dim3 g2(D_ / 512, NC_, B_);    // 2 x 128 x 4 = 1024 blocks
    chunk_reduce<<<g2, 256, 0, stream>>>((const unsigned int*)cvb, CVagg);

    dim3 g3(D_ / 256, 1, B_);      // 4 x 1 x 4
    chunk_scan<<<g3, 256, 0, stream>>>(CVagg, P);

    chunk_apply<<<g2, 256, 0, stream>>>((const unsigned int*)cvb, P, out);
}